// Round 1
// 252.744 us; speedup vs baseline: 1.0358x; 1.0358x over previous
//
#include <hip/hip_runtime.h>

// BoxFilter: 21x21 all-ones box, circular pad, x: f32[8,1,2048,2048].
// v3: vectorize everything. Phase 1: float4 column-group loads (1 KB/wave-instr),
// running vertical sums, b128 LDS writes. Phase 2: b128 LDS reads of a 40-float
// aligned window per 16-col chunk, sliding horizontal sums, float4 stores.
// Tile 128x64, LDS 39.9 KB -> 4 blocks/CU.

#define HH 2048
#define WW 2048
#define RAD 10
#define DIAM 21
#define TH 64
#define TW 128
#define NC4 38          // float4 colsum slots: image cols [w0-12, w0+139]
#define SSTR 156        // LDS row stride (dwords); 156%32=28 -> <=4-way b128 aliasing

__global__ __launch_bounds__(256) void box_filter_v3(
    const float* __restrict__ x, float* __restrict__ out) {
  __shared__ float sCS[TH * SSTR];  // 39936 B: colsum[r][a], a = image col - (w0-12)

  const int n = blockIdx.z;
  const int h0 = blockIdx.y * TH;
  const int w0 = blockIdx.x * TW;
  const float* __restrict__ xp = x + (size_t)n * (HH * WW);
  float* __restrict__ op = out + (size_t)n * (HH * WW);
  const int tid = threadIdx.x;

  // ---- Phase 1: vertical sliding sums, float4-vectorized columns.
  // 38 col-quads x 4 row-groups = 152 tasks. Each task: 36 float4 row loads
  // (coalesced, 16B/lane), 21-tap running sum slid over 16 output rows,
  // b128 writes into LDS.
  if (tid < NC4 * 4) {
    const int c4 = tid % NC4;            // 0..37 (consecutive lanes -> consecutive quads)
    const int g = tid / NC4;             // row-group 0..3
    const int gc = (w0 - 12 + 4 * c4) & (WW - 1);  // circular in W, 16B aligned
    const int rbase = h0 + 16 * g - RAD;
    float4 v[36];
#pragma unroll
    for (int k = 0; k < 36; ++k)
      v[k] = *(const float4*)(xp + (size_t)((rbase + k) & (HH - 1)) * WW + gc);
    float4 s = v[0];
#pragma unroll
    for (int k = 1; k < DIAM; ++k) {
      s.x += v[k].x; s.y += v[k].y; s.z += v[k].z; s.w += v[k].w;
    }
    *(float4*)&sCS[(16 * g) * SSTR + 4 * c4] = s;
#pragma unroll
    for (int i = 1; i < 16; ++i) {
      s.x += v[i + 20].x - v[i - 1].x;
      s.y += v[i + 20].y - v[i - 1].y;
      s.z += v[i + 20].z - v[i - 1].z;
      s.w += v[i + 20].w - v[i - 1].w;
      *(float4*)&sCS[(16 * g + i) * SSTR + 4 * c4] = s;
    }
  }
  __syncthreads();

  // ---- Phase 2: horizontal sliding sums. thread -> (row r, two 16-col chunks).
  // Window of 40 colsums loaded as 10 aligned b128; output col j (in chunk)
  // sums window[j+2 .. j+22].
  {
    const int r = tid >> 2;
    const float* row = &sCS[r * SSTR];
    float* orow = &op[(size_t)(h0 + r) * WW + w0];
#pragma unroll
    for (int ii = 0; ii < 2; ++ii) {
      const int cg = (tid & 3) + 4 * ii;  // 0..7
      __align__(16) float w[40];
#pragma unroll
      for (int k = 0; k < 10; ++k)
        *(float4*)&w[4 * k] = *(const float4*)&row[16 * cg + 4 * k];
      float s = w[2];
#pragma unroll
      for (int k = 3; k <= 22; ++k) s += w[k];
      float o[16];
      o[0] = s;
#pragma unroll
      for (int j = 1; j < 16; ++j) {
        s += w[j + 22] - w[j + 1];
        o[j] = s;
      }
      float4* dst = (float4*)&orow[16 * cg];
#pragma unroll
      for (int q = 0; q < 4; ++q)
        dst[q] = make_float4(o[4 * q], o[4 * q + 1], o[4 * q + 2], o[4 * q + 3]);
    }
  }
}

extern "C" void kernel_launch(void* const* d_in, const int* in_sizes, int n_in,
                              void* d_out, int out_size, void* d_ws, size_t ws_size,
                              hipStream_t stream) {
  const float* x = (const float*)d_in[0];
  float* out = (float*)d_out;
  dim3 grid(WW / TW, HH / TH, 8);
  dim3 block(256);
  hipLaunchKernelGGL(box_filter_v3, grid, block, 0, stream, x, out);
}